// Round 1
// baseline (353.726 us; speedup 1.0000x reference)
//
#include <hip/hip_runtime.h>
#include <hip/hip_bf16.h>

typedef __attribute__((ext_vector_type(8))) short bf16x8;
typedef __attribute__((ext_vector_type(4))) float f32x4;
typedef __attribute__((ext_vector_type(8))) unsigned short u16x8;

#define B_DIM 8192
#define H_DIM 1024
#define K_DIM 2048
#define N_DIM 4096
#define BH (B_DIM * H_DIM)
#define NT 32   // K tiles of 64

__device__ __forceinline__ unsigned short f2bf(float f) {
    union { float f; unsigned u; } v; v.f = f;
    unsigned r = v.u + 0x7FFFu + ((v.u >> 16) & 1u);   // round-to-nearest-even
    return (unsigned short)(r >> 16);
}

__device__ __forceinline__ void gload16(const void* g, void* l) {
    __builtin_amdgcn_global_load_lds(
        (const __attribute__((address_space(1))) void*)g,
        (__attribute__((address_space(3))) void*)l, 16, 0, 0);
}

// ---------------------------------------------------------------------------
// prep: UNCHANGED from previous round (known-good).
// blocks [0,8192): pack [x|h] fp32 -> bf16 A[8192][2048] (16B stores)
// blocks [8192,10240): W=[Wx;Wh] -> bf16 Bperm (gate-permuted B^T)
//   R = jb*128 + (jj>>4)*64 + gate*16 + (jj&15),  Bperm[R][k] = W[k][n]
// ---------------------------------------------------------------------------
__global__ void prep(const float* __restrict__ x, const float* __restrict__ h,
                     const float* __restrict__ Wx, const float* __restrict__ Wh,
                     unsigned short* __restrict__ Abf, unsigned short* __restrict__ Bperm) {
    __shared__ float tile[64][65];
    const int t = threadIdx.x;
    if (blockIdx.x < 8192) {
        int gid = blockIdx.x * 256 + t;
        size_t e = (size_t)gid * 8;
        int m   = gid >> 8;
        int col = (gid & 255) * 8;
        int p   = col >> 10;
        int k   = col & 1023;
        const float* src = (p ? h : x) + (size_t)m * 1024 + k;
        float4 v0 = *(const float4*)src;
        float4 v1 = *(const float4*)(src + 4);
        u16x8 o = { f2bf(v0.x), f2bf(v0.y), f2bf(v0.z), f2bf(v0.w),
                    f2bf(v1.x), f2bf(v1.y), f2bf(v1.z), f2bf(v1.w) };
        *(u16x8*)(Abf + e) = o;
        return;
    }
    const int bz = blockIdx.x - 8192;
    const int k0 = (bz & 31) * 64;
    const int n0 = (bz >> 5) * 64;
#pragma unroll
    for (int it = 0; it < 4; ++it) {
        int lin = it * 256 + t;
        int kl  = lin >> 4;
        int n4  = lin & 15;
        int k   = k0 + kl;
        const float* src = (k < 1024) ? (Wx + (size_t)k * 4096 + n0 + n4 * 4)
                                      : (Wh + (size_t)(k - 1024) * 4096 + n0 + n4 * 4);
        float4 v = *(const float4*)src;
        tile[kl][n4 * 4 + 0] = v.x;
        tile[kl][n4 * 4 + 1] = v.y;
        tile[kl][n4 * 4 + 2] = v.z;
        tile[kl][n4 * 4 + 3] = v.w;
    }
    __syncthreads();
#pragma unroll
    for (int it = 0; it < 2; ++it) {
        int lin = it * 256 + t;
        int nl  = lin >> 3;
        int ch  = lin & 7;
        int n    = n0 + nl;
        int gate = n >> 10;
        int j    = n & 1023;
        int jb   = j >> 5;
        int jj   = j & 31;
        int R    = jb * 128 + (jj >> 4) * 64 + gate * 16 + (jj & 15);
        u16x8 o;
#pragma unroll
        for (int q = 0; q < 8; ++q) o[q] = f2bf(tile[ch * 8 + q][nl]);
        *(u16x8*)(Bperm + (size_t)R * 2048 + k0 + ch * 8) = o;
    }
}

// ---------------------------------------------------------------------------
// 256x256 tile, BK=64, 8 waves (2M x 4N), 8-phase schedule, counted vmcnt.
// LDS: 2 buffers x 256x64 bf16 for A and B = 128 KiB total.
//   buf0 <- even K-tiles, buf1 <- odd K-tiles.
// Swizzle (identical involution to previous kernel, 0 bank conflicts):
//   physical chunk p of row holds logical chunk p ^ (row&7); achieved with
//   linear gload_lds dest + pre-swizzled global source column, and the same
//   XOR on the ds_read_b128 fragment address.
// Phase pattern per K-tile (quad = 4tm x 2tn x 2ks = 16 MFMA):
//   Pa: read A-low(8)+B-low(4), quad(0,0)   Pb: read A-high(8), quad(4,0)
//   Pc: read B-high(4),        quad(4,2)   Pd: no reads,       quad(0,2)
// Stage slots (one half-tile = 2 gloads/thread per phase), WAR-safe:
//   P1: B0(t+1)  P2: B1(t+1)  P3: A0(t+2)  P4: A1(t+2) [vmcnt(4)]
//   P5: B0(t+2)  P6: B1(t+2)  P7: A0(t+3)  P8: A1(t+3) [vmcnt(4)]
// Gate math: 6 stage-phases (12 loads) outstanding at each gate; oldest 4
// half-tiles (8 loads) must complete -> s_waitcnt vmcnt(4). Never drain to 0
// in the loop.
// ---------------------------------------------------------------------------
#define VMW(N) asm volatile("s_waitcnt vmcnt(" #N ")" ::: "memory")
#define BAR() __builtin_amdgcn_s_barrier()

#define LD_A(BUF, TMB) do { \
  _Pragma("unroll") \
  for (int _tm = 0; _tm < 4; ++_tm) \
    _Pragma("unroll") \
    for (int _ks = 0; _ks < 2; ++_ks) \
      af[(TMB) + _tm][_ks] = *(const bf16x8*)(lsA + (BUF) * 16384 + \
          (wm * 128 + ((TMB) + _tm) * 16 + fRow) * 64 + ((_ks * 4 + q4) ^ rx) * 8); \
} while (0)

#define LD_B(BUF, TNB) do { \
  _Pragma("unroll") \
  for (int _tn = 0; _tn < 2; ++_tn) \
    _Pragma("unroll") \
    for (int _ks = 0; _ks < 2; ++_ks) \
      bfr[_tn][_ks] = *(const bf16x8*)(lsB + (BUF) * 16384 + \
          (wn * 64 + ((TNB) + _tn) * 16 + fRow) * 64 + ((_ks * 4 + q4) ^ rx) * 8); \
} while (0)

#define STAGE_A(BUF, H, T) do { \
  gload16(Abf + (size_t)(m0 + (H) * 128 + sRow) * K_DIM + (T) * 64 + sChunk, \
          lsA + (BUF) * 16384 + (H) * 8192 + wave * 512); \
  gload16(Abf + (size_t)(m0 + (H) * 128 + 64 + sRow) * K_DIM + (T) * 64 + sChunk, \
          lsA + (BUF) * 16384 + (H) * 8192 + 4096 + wave * 512); \
} while (0)

#define STAGE_B(BUF, H, T) do { \
  gload16(Bperm + (size_t)(r0 + (H) * 128 + sRow) * K_DIM + (T) * 64 + sChunk, \
          lsB + (BUF) * 16384 + (H) * 8192 + wave * 512); \
  gload16(Bperm + (size_t)(r0 + (H) * 128 + 64 + sRow) * K_DIM + (T) * 64 + sChunk, \
          lsB + (BUF) * 16384 + (H) * 8192 + 4096 + wave * 512); \
} while (0)

// ks outer -> 8 independent MFMAs between dependent pairs on the same acc.
#define MFMA_QUAD(TMB, TNB) do { \
  __builtin_amdgcn_s_setprio(1); \
  _Pragma("unroll") \
  for (int _ks = 0; _ks < 2; ++_ks) \
    _Pragma("unroll") \
    for (int _tm = 0; _tm < 4; ++_tm) \
      _Pragma("unroll") \
      for (int _tn = 0; _tn < 2; ++_tn) \
        acc[(TMB) + _tm][(TNB) + _tn] = __builtin_amdgcn_mfma_f32_16x16x32_bf16( \
            af[(TMB) + _tm][_ks], bfr[_tn][_ks], acc[(TMB) + _tm][(TNB) + _tn], 0, 0, 0); \
  __builtin_amdgcn_s_setprio(0); \
} while (0)

__global__ __launch_bounds__(512, 2) void lstm_fused(
    const unsigned short* __restrict__ Abf,   // [8192][2048] bf16
    const unsigned short* __restrict__ Bperm, // [4096][2048] bf16 (gate-permuted B^T)
    const float* __restrict__ bx, const float* __restrict__ bh,
    const float* __restrict__ cin, float* __restrict__ out) {
    __shared__ unsigned short lsA[2 * 256 * 64];   // 64 KiB
    __shared__ unsigned short lsB[2 * 256 * 64];   // 64 KiB

    const int tid  = threadIdx.x;
    const int wave = tid >> 6;
    const int lane = tid & 63;
    const int wm   = wave >> 2;                 // 0..1 (M half)
    const int wn   = wave & 3;                  // 0..3 (N quarter)

    // Bijective XCD swizzle: 512 blocks % 8 == 0. Within an XCD chunk we walk
    // M-tiles (shared Bperm panel stays hot in that XCD's L2).
    const int bid = blockIdx.x;
    const int swz = (bid & 7) * 64 + (bid >> 3);
    const int bm  = swz & 31;                   // M tile 0..31
    const int bn  = swz >> 5;                   // N tile 0..15
    const int m0  = bm * 256;
    const int r0  = bn * 256;                   // Bperm row base

    // staging: thread -> (row = it*64 + tid>>3, physical chunk = tid&7)
    // source logical chunk = phys ^ (row&7)  (pre-swizzled global column)
    const int sRow   = tid >> 3;                              // 0..63
    const int sChunk = ((tid & 7) ^ ((tid >> 3) & 7)) * 8;    // element offset

    // fragment read geometry
    const int fRow = lane & 15;
    const int q4   = lane >> 4;                 // 0..3
    const int rx   = fRow & 7;                  // row XOR key

    f32x4 acc[8][4];
#pragma unroll
    for (int i = 0; i < 8; ++i)
#pragma unroll
        for (int j = 0; j < 4; ++j) acc[i][j] = (f32x4){0.f, 0.f, 0.f, 0.f};

    bf16x8 af[8][2];    // all A fragments of current tile (no LDS re-read)
    bf16x8 bfr[2][2];   // current B pair (low or high)

    // ---- prologue: t0 full into buf0, A-halves of t1 into buf1
    STAGE_A(0, 0, 0); STAGE_A(0, 1, 0); STAGE_B(0, 0, 0); STAGE_B(0, 1, 0);
    STAGE_A(1, 0, 1); STAGE_A(1, 1, 1);
    VMW(4);                                      // t0 (8 loads) complete
    BAR();

    // ---- main loop: 15 iterations, tiles 0..29; prefetch t+1..t+3
    for (int i = 0; i < 15; ++i) {
        const int t = 2 * i;
        // P1
        LD_A(0, 0); LD_B(0, 0);
        STAGE_B(1, 0, t + 1);
        BAR();
        MFMA_QUAD(0, 0);
        BAR();
        // P2
        LD_A(0, 4);
        STAGE_B(1, 1, t + 1);
        BAR();
        MFMA_QUAD(4, 0);
        BAR();
        // P3
        LD_B(0, 2);
        STAGE_A(0, 0, t + 2);
        BAR();
        MFMA_QUAD(4, 2);
        BAR();
        // P4
        STAGE_A(0, 1, t + 2);
        BAR();
        MFMA_QUAD(0, 2);
        VMW(4);                                  // t+1 halves complete
        BAR();
        // P5
        LD_A(1, 0); LD_B(1, 0);
        STAGE_B(0, 0, t + 2);
        BAR();
        MFMA_QUAD(0, 0);
        BAR();
        // P6
        LD_A(1, 4);
        STAGE_B(0, 1, t + 2);
        BAR();
        MFMA_QUAD(4, 0);
        BAR();
        // P7
        LD_B(1, 2);
        STAGE_A(1, 0, t + 3);
        BAR();
        MFMA_QUAD(4, 2);
        BAR();
        // P8
        STAGE_A(1, 1, t + 3);
        BAR();
        MFMA_QUAD(0, 2);
        VMW(4);                                  // t+2 halves complete
        BAR();
    }

    // ---- epilogue: tile 30 (buf0, gated by last loop vmcnt(4)), then tile 31
    STAGE_B(1, 0, 31); STAGE_B(1, 1, 31);        // buf1 B free since P7 of i=14
    LD_A(0, 0); LD_B(0, 0); MFMA_QUAD(0, 0);
    LD_A(0, 4);             MFMA_QUAD(4, 0);
    LD_B(0, 2);             MFMA_QUAD(4, 2); MFMA_QUAD(0, 2);
    VMW(0);                                      // drain A(31)+B(31)
    BAR();
    LD_A(1, 0); LD_B(1, 0); MFMA_QUAD(0, 0);
    LD_A(1, 4);             MFMA_QUAD(4, 0);
    LD_B(1, 2);             MFMA_QUAD(4, 2); MFMA_QUAD(0, 2);

    // ---- LSTM epilogue: tn indexes gate {i,f,g,o}; j fixed per lane.
    const int j = bn * 64 + (wn >> 1) * 32 + (wn & 1) * 16 + fRow;
    const float b_i = bx[j] + bh[j];
    const float b_f = bx[1024 + j] + bh[1024 + j];
    const float b_g = bx[2048 + j] + bh[2048 + j];
    const float b_o = bx[3072 + j] + bh[3072 + j];
#pragma unroll
    for (int tm = 0; tm < 8; ++tm) {
#pragma unroll
        for (int r = 0; r < 4; ++r) {
            const int row = m0 + wm * 128 + tm * 16 + q4 * 4 + r;
            float vi = acc[tm][0][r] + b_i;
            float vf = acc[tm][1][r] + b_f;
            float vg = acc[tm][2][r] + b_g;
            float vo = acc[tm][3][r] + b_o;
            float ig = 1.f / (1.f + __expf(-vi));
            float fg = 1.f / (1.f + __expf(-vf));
            float e2g = __expf(2.f * fminf(fmaxf(vg, -15.f), 15.f));
            float gg = (e2g - 1.f) / (e2g + 1.f);
            float og = 1.f / (1.f + __expf(-vo));
            float cn = fg * cin[(size_t)row * 1024 + j] + ig * gg;
            float e2c = __expf(2.f * fminf(fmaxf(cn, -15.f), 15.f));
            float hn = og * ((e2c - 1.f) / (e2c + 1.f));
            out[(size_t)row * 1024 + j] = og;
            out[(size_t)BH + (size_t)row * 1024 + j] = hn;
            out[(size_t)2 * BH + (size_t)row * 1024 + j] = cn;
        }
    }
}

extern "C" void kernel_launch(void* const* d_in, const int* in_sizes, int n_in,
                              void* d_out, int out_size, void* d_ws, size_t ws_size,
                              hipStream_t stream) {
    const float* x  = (const float*)d_in[0];
    const float* h  = (const float*)d_in[1];
    const float* c  = (const float*)d_in[2];
    const float* Wx = (const float*)d_in[3];
    const float* Wh = (const float*)d_in[4];
    const float* bx = (const float*)d_in[5];
    const float* bh = (const float*)d_in[6];
    float* out = (float*)d_out;

    unsigned short* Abf   = (unsigned short*)d_ws;                                      // 32 MB
    unsigned short* Bperm = (unsigned short*)((char*)d_ws + (size_t)B_DIM * K_DIM * 2); // 16 MB

    hipLaunchKernelGGL(prep, dim3(8192 + 2048), dim3(256), 0, stream, x, h, Wx, Wh, Abf, Bperm);
    hipLaunchKernelGGL(lstm_fused, dim3(512), dim3(512), 0, stream,
                       Abf, Bperm, bx, bh, c, out);
}